// Round 7
// baseline (905.294 us; speedup 1.0000x reference)
//
#include <hip/hip_runtime.h>
#include <hip/hip_fp16.h>
#include <math.h>

#define NEG_SLOPE 0.2f
#define BSTRIDE 6144   // fixed slots per 256-node bucket (mean 4337, 27 sigma margin)
#define L2E 1.4426950408889634f   // log2(e): att coeffs pre-scaled so loops use exp2

typedef _Float16 f16x8 __attribute__((ext_vector_type(8)));
typedef float    f32x4 __attribute__((ext_vector_type(4)));

__device__ __forceinline__ void get_edge(const int* __restrict__ ei, int E, int e,
                                         int& s, int& d) {
    if (e < E) { s = ei[e]; d = ei[E + e]; }
    else       { s = e - E; d = e - E; }
}

// ========== merged GEMM1 + bucket_scatter (round-4/6 proven) ==========
// blocks [0, gblocks)   : gemm1  h1 = x@W1 (f16) + att1 coeffs (L2E-scaled)
// block  gblocks        : aux: layer-2 att projections wa/wb (L2E-scaled)
// blocks > gblocks      : LDS-staged bucket scatter (global cursors, memset'd)
union G1SMem {
    unsigned int sWu[4096];                                  // gemm path: 16 KB
    struct {
        int lhist[256], lbase[256], lrank[256], gbase[256];  // scatter path
        unsigned int sbuf[4096];
        int saddr[4096];
    } sc;
};

__global__ __launch_bounds__(256) void g1s_kernel(const float* __restrict__ x,
                                                  const float* __restrict__ W,
                                                  const float* __restrict__ asrc,
                                                  const float* __restrict__ adst,
                                                  _Float16* __restrict__ hout,
                                                  float* __restrict__ av,
                                                  float* __restrict__ bv, int N,
                                                  int gblocks,
                                                  const float* __restrict__ W2,
                                                  const float* __restrict__ as2,
                                                  const float* __restrict__ ad2,
                                                  float* __restrict__ wa,
                                                  float* __restrict__ wb,
                                                  int* __restrict__ bcur,
                                                  const int* __restrict__ ei, int E, int ET,
                                                  unsigned int* __restrict__ bstore,
                                                  int nbuck) {
    __shared__ G1SMem sm;
    int t = threadIdx.x;

    if (blockIdx.x == (unsigned)gblocks) {
        // ---- aux: layer-2 attention projections (L2E-scaled) ----
        if (t < 64) {
            const float* wr = W2 + t * 128;
            float sa = 0.f, sb = 0.f;
#pragma unroll 8
            for (int c = 0; c < 128; ++c) {
                float w = wr[c];
                sa = fmaf(w, as2[c], sa);
                sb = fmaf(w, ad2[c], sb);
            }
            wa[t] = sa * L2E; wb[t] = sb * L2E;
        }
        return;
    }

    if (blockIdx.x > (unsigned)gblocks) {
        // ---- bucket scatter (LDS-staged, bucket-grouped writes) ----
        int sblk = blockIdx.x - gblocks - 1;
        int start = sblk * 4096;
        int cnt = ET - start; if (cnt > 4096) cnt = 4096;
        sm.sc.lhist[t] = 0; sm.sc.lrank[t] = 0;
        __syncthreads();
        int mybuck[16]; unsigned int myval[16];
#pragma unroll
        for (int k = 0; k < 16; ++k) {
            int e = start + t + k * 256;
            mybuck[k] = -1;
            if (e < ET) {
                int s, d; get_edge(ei, E, e, s, d);
                mybuck[k] = d >> 8;
                myval[k] = ((unsigned int)d << 16) | (unsigned int)s;
                atomicAdd(&sm.sc.lhist[mybuck[k]], 1);
            }
        }
        __syncthreads();
        int v = sm.sc.lhist[t];
        sm.sc.lbase[t] = v;
        __syncthreads();
        for (int off = 1; off < 256; off <<= 1) {
            int u = (t >= off) ? sm.sc.lbase[t - off] : 0;
            __syncthreads();
            sm.sc.lbase[t] += u;
            __syncthreads();
        }
        int excl = sm.sc.lbase[t] - v;
        if (t < nbuck && v > 0)
            sm.sc.gbase[t] = t * BSTRIDE + atomicAdd(&bcur[t], v);
        __syncthreads();
        sm.sc.lbase[t] = excl;
        __syncthreads();
#pragma unroll
        for (int k = 0; k < 16; ++k) {
            int b = mybuck[k];
            if (b >= 0) {
                int r = atomicAdd(&sm.sc.lrank[b], 1);
                int idx = sm.sc.lbase[b] + r;
                sm.sc.sbuf[idx] = myval[k];
                sm.sc.saddr[idx] = sm.sc.gbase[b] + r;
            }
        }
        __syncthreads();
        for (int j = t; j < cnt; j += 256)
            bstore[sm.sc.saddr[j]] = sm.sc.sbuf[j];
        return;
    }

    // ---- gemm1 ----
    for (int p = t; p < 4096; p += 256) {
        int frag = p >> 8;
        int lane = (p >> 2) & 63;
        int j2   = p & 3;
        int chunk = frag >> 2, nt = frag & 3;
        int k = chunk * 32 + ((lane >> 4) << 3) + (j2 << 1);
        int n = nt * 16 + (lane & 15);
        union { _Float16 h[2]; unsigned int u; } pk;
        pk.h[0] = (_Float16)W[k * 64 + n];
        pk.h[1] = (_Float16)W[(k + 1) * 64 + n];
        sm.sWu[p] = pk.u;
    }
    __syncthreads();

    int lane = t & 63;
    int wid  = t >> 6;
    int rbase = blockIdx.x * 64 + wid * 16;
    int l15 = lane & 15, quad = lane >> 4;
    int rA = rbase + l15; if (rA >= N) rA = N - 1;

    const unsigned int* fragbase = &sm.sWu[lane * 4];
    f32x4 z = {0.f, 0.f, 0.f, 0.f};
    f32x4 acc[4] = {z, z, z, z};

#pragma unroll
    for (int chunk = 0; chunk < 4; ++chunk) {
        const float* xp = x + (size_t)rA * 128 + chunk * 32 + quad * 8;
        float4 f0 = *((const float4*)xp);
        float4 f1 = *((const float4*)(xp + 4));
        f16x8 af;
        af[0] = (_Float16)f0.x; af[1] = (_Float16)f0.y;
        af[2] = (_Float16)f0.z; af[3] = (_Float16)f0.w;
        af[4] = (_Float16)f1.x; af[5] = (_Float16)f1.y;
        af[6] = (_Float16)f1.z; af[7] = (_Float16)f1.w;
#pragma unroll
        for (int tt = 0; tt < 4; ++tt) {
            f16x8 bf = *((const f16x8*)(fragbase + (chunk * 4 + tt) * 256));
            acc[tt] = __builtin_amdgcn_mfma_f32_16x16x32_f16(af, bf, acc[tt], 0, 0, 0);
        }
    }

    float asc[4], adc[4];
#pragma unroll
    for (int tt = 0; tt < 4; ++tt) {
        asc[tt] = asrc[tt * 16 + l15] * L2E;
        adc[tt] = adst[tt * 16 + l15] * L2E;
    }
#pragma unroll
    for (int reg = 0; reg < 4; ++reg) {
        int r = rbase + quad * 4 + reg;
        bool ok = (r < N);
#pragma unroll
        for (int tt = 0; tt < 4; ++tt) {
            float v = acc[tt][reg];
            if (ok) hout[(size_t)r * 64 + tt * 16 + l15] = (_Float16)v;
            float pa = v * asc[tt], pb = v * adc[tt];
            pa += __shfl_xor(pa, 1); pb += __shfl_xor(pb, 1);
            pa += __shfl_xor(pa, 2); pb += __shfl_xor(pb, 2);
            pa += __shfl_xor(pa, 4); pb += __shfl_xor(pb, 4);
            if (ok && (lane & 7) == 0) {
                int head = tt * 2 + (l15 >> 3);
                av[r * 8 + head] = pa;
                bv[r * 8 + head] = pb;
            }
        }
    }
}

// ========== layer-1: edge-parallel LDS scatter-accumulate + epilogue ==========
// Block = half-bucket (128 nodes). Streams the bucket's bstore segment
// coalesced; 8-lane group per edge (lane gl = head gl); w*h accumulated via
// LDS f32 atomics into acc[128][66] (pad 66: cross-group bank shift).
// Epilogue: softmax divide + b1 + elu -> out1(f16), att2 coeffs -> av2/bv2.
__global__ __launch_bounds__(512) void agg1e_kernel(const unsigned int* __restrict__ bstore,
                                                    const int* __restrict__ bcur,
                                                    const float* __restrict__ av,
                                                    const float* __restrict__ bv,
                                                    const __half* __restrict__ h1,
                                                    const float* __restrict__ b1,
                                                    const float* __restrict__ wa,
                                                    const float* __restrict__ wb,
                                                    _Float16* __restrict__ out1,
                                                    float* __restrict__ av2,
                                                    float* __restrict__ bv2, int N) {
    __shared__ float acc[128][66];   // 33.8 KB
    __shared__ float sS[128][8];     // 4 KB
    __shared__ float sBv[128][8];    // 4 KB
    int t = threadIdx.x;
    int b = blockIdx.x >> 1, h = blockIdx.x & 1;
    int nbase = (b << 8) + (h << 7);

    for (int i = t; i < 128 * 66; i += 512) (&acc[0][0])[i] = 0.f;
    for (int i = t; i < 1024; i += 512) {
        (&sS[0][0])[i] = 0.f;
        int node = nbase + (i >> 3);
        (&sBv[0][0])[i] = (node < N) ? bv[node * 8 + (i & 7)] : 0.f;
    }
    __syncthreads();

    int nb = bcur[b]; if (nb > BSTRIDE) nb = BSTRIDE;
    const unsigned int* seg = bstore + (size_t)b * BSTRIDE;
    int grp = t >> 3, gl = t & 7;
    const uint4* hrow = (const uint4*)h1;

    for (int i = grp; i < nb; i += 64) {
        unsigned int pk = seg[i];
        int local = (pk >> 16) & 255;
        if ((local >> 7) != h) continue;
        int l7 = local & 127;
        int src = (int)(pk & 0xFFFFu);
        float l = av[src * 8 + gl] + sBv[l7][gl];
        l = l > 0.f ? l : NEG_SLOPE * l;
        float w = __builtin_amdgcn_exp2f(l);
        atomicAdd(&sS[l7][gl], w);
        uint4 hv = hrow[(size_t)src * 8 + gl];
        float2 f0 = __half22float2(*(const __half2*)&hv.x);
        float2 f1 = __half22float2(*(const __half2*)&hv.y);
        float2 f2 = __half22float2(*(const __half2*)&hv.z);
        float2 f3 = __half22float2(*(const __half2*)&hv.w);
        float* ap = &acc[l7][gl * 8];
        atomicAdd(ap + 0, w * f0.x); atomicAdd(ap + 1, w * f0.y);
        atomicAdd(ap + 2, w * f1.x); atomicAdd(ap + 3, w * f1.y);
        atomicAdd(ap + 4, w * f2.x); atomicAdd(ap + 5, w * f2.y);
        atomicAdd(ap + 6, w * f3.x); atomicAdd(ap + 7, w * f3.y);
    }
    __syncthreads();

    // ---- epilogue: group (8 lanes) per node, 2 passes over 128 nodes ----
    for (int pass = 0; pass < 2; ++pass) {
        int nl = pass * 64 + grp;
        int node = nbase + nl;
        if (node >= N) continue;
        float s = sS[nl][gl];
        float inv = s > 0.f ? __builtin_amdgcn_rcpf(s) : 0.f;
        const float* ap = &acc[nl][gl * 8];
        float4 bb0 = ((const float4*)b1)[gl * 2];
        float4 bb1 = ((const float4*)b1)[gl * 2 + 1];
        float v0 = ap[0] * inv + bb0.x, v1 = ap[1] * inv + bb0.y;
        float v2 = ap[2] * inv + bb0.z, v3 = ap[3] * inv + bb0.w;
        float v4 = ap[4] * inv + bb1.x, v5 = ap[5] * inv + bb1.y;
        float v6 = ap[6] * inv + bb1.z, v7 = ap[7] * inv + bb1.w;
        v0 = v0 > 0.f ? v0 : __expf(v0) - 1.f; v1 = v1 > 0.f ? v1 : __expf(v1) - 1.f;
        v2 = v2 > 0.f ? v2 : __expf(v2) - 1.f; v3 = v3 > 0.f ? v3 : __expf(v3) - 1.f;
        v4 = v4 > 0.f ? v4 : __expf(v4) - 1.f; v5 = v5 > 0.f ? v5 : __expf(v5) - 1.f;
        v6 = v6 > 0.f ? v6 : __expf(v6) - 1.f; v7 = v7 > 0.f ? v7 : __expf(v7) - 1.f;
        float4 wa0 = ((const float4*)wa)[gl * 2], wa1 = ((const float4*)wa)[gl * 2 + 1];
        float4 wb0 = ((const float4*)wb)[gl * 2], wb1 = ((const float4*)wb)[gl * 2 + 1];
        float pa = v0 * wa0.x + v1 * wa0.y + v2 * wa0.z + v3 * wa0.w
                 + v4 * wa1.x + v5 * wa1.y + v6 * wa1.z + v7 * wa1.w;
        float pb = v0 * wb0.x + v1 * wb0.y + v2 * wb0.z + v3 * wb0.w
                 + v4 * wb1.x + v5 * wb1.y + v6 * wb1.z + v7 * wb1.w;
        pa += __shfl_xor(pa, 1); pb += __shfl_xor(pb, 1);
        pa += __shfl_xor(pa, 2); pb += __shfl_xor(pb, 2);
        pa += __shfl_xor(pa, 4); pb += __shfl_xor(pb, 4);
        if (gl == 0) { av2[node] = pa; bv2[node] = pb; }
        f16x8 o;
        o[0] = (_Float16)v0; o[1] = (_Float16)v1; o[2] = (_Float16)v2; o[3] = (_Float16)v3;
        o[4] = (_Float16)v4; o[5] = (_Float16)v5; o[6] = (_Float16)v6; o[7] = (_Float16)v7;
        ((f16x8*)out1)[(size_t)node * 8 + gl] = o;
    }
}

// ========== layer-2: edge-parallel LDS accumulate + fused GEMM -> dout ==========
// Same half-bucket structure; single head. After normalize, 8 waves MFMA the
// 128-row tile (A-frags converted f32->f16 straight from LDS acc).
__global__ __launch_bounds__(512) void agg2e_kernel(const unsigned int* __restrict__ bstore,
                                                    const int* __restrict__ bcur,
                                                    const float* __restrict__ av,
                                                    const float* __restrict__ bv,
                                                    const __half* __restrict__ out1,
                                                    const float* __restrict__ W,
                                                    const float* __restrict__ b2,
                                                    float* __restrict__ dout, int N) {
    __shared__ float acc[128][66];      // 33.8 KB
    __shared__ float sS[128];
    __shared__ float sInv[128];
    __shared__ float sBv[128];
    __shared__ unsigned int sWu[4096];  // 16 KB
    int t = threadIdx.x;
    int b = blockIdx.x >> 1, h = blockIdx.x & 1;
    int nbase = (b << 8) + (h << 7);

    // stage W2 frags (same layout as old gemm2)
    for (int p = t; p < 4096; p += 512) {
        int frag = p >> 8;
        int ln = (p >> 2) & 63;
        int j2 = p & 3;
        int chunk = frag >> 3, nt = frag & 7;
        int k = chunk * 32 + ((ln >> 4) << 3) + (j2 << 1);
        int n = nt * 16 + (ln & 15);
        union { _Float16 h2[2]; unsigned int u; } pk;
        pk.h2[0] = (_Float16)W[k * 128 + n];
        pk.h2[1] = (_Float16)W[(k + 1) * 128 + n];
        sWu[p] = pk.u;
    }
    for (int i = t; i < 128 * 66; i += 512) (&acc[0][0])[i] = 0.f;
    if (t < 128) {
        sS[t] = 0.f;
        int node = nbase + t;
        sBv[t] = (node < N) ? bv[node] : 0.f;
    }
    __syncthreads();

    int nb = bcur[b]; if (nb > BSTRIDE) nb = BSTRIDE;
    const unsigned int* seg = bstore + (size_t)b * BSTRIDE;
    int grp = t >> 3, gl = t & 7;
    const uint4* hrow = (const uint4*)out1;

    for (int i = grp; i < nb; i += 64) {
        unsigned int pk = seg[i];
        int local = (pk >> 16) & 255;
        if ((local >> 7) != h) continue;
        int l7 = local & 127;
        int src = (int)(pk & 0xFFFFu);
        float l = av[src] + sBv[l7];
        l = l > 0.f ? l : NEG_SLOPE * l;
        float w = __builtin_amdgcn_exp2f(l);
        if (gl == 0) atomicAdd(&sS[l7], w);
        uint4 hv = hrow[(size_t)src * 8 + gl];
        float2 f0 = __half22float2(*(const __half2*)&hv.x);
        float2 f1 = __half22float2(*(const __half2*)&hv.y);
        float2 f2 = __half22float2(*(const __half2*)&hv.z);
        float2 f3 = __half22float2(*(const __half2*)&hv.w);
        float* ap = &acc[l7][gl * 8];
        atomicAdd(ap + 0, w * f0.x); atomicAdd(ap + 1, w * f0.y);
        atomicAdd(ap + 2, w * f1.x); atomicAdd(ap + 3, w * f1.y);
        atomicAdd(ap + 4, w * f2.x); atomicAdd(ap + 5, w * f2.y);
        atomicAdd(ap + 6, w * f3.x); atomicAdd(ap + 7, w * f3.y);
    }
    __syncthreads();

    if (t < 128) sInv[t] = sS[t] > 0.f ? __builtin_amdgcn_rcpf(sS[t]) : 0.f;
    __syncthreads();
    for (int i = t; i < 8192; i += 512) {
        int nl = i >> 6;
        acc[nl][i & 63] *= sInv[nl];
    }
    __syncthreads();

    // ---- MFMA: 8 waves, wave w = rows w*16..w*16+16, all 128 cols ----
    int lane = t & 63, wid = t >> 6;
    int l15 = lane & 15, quad = lane >> 4;
    const unsigned int* fragbase = &sWu[lane * 4];
    f32x4 z = {0.f, 0.f, 0.f, 0.f};
    f32x4 accr[8] = {z, z, z, z, z, z, z, z};

#pragma unroll
    for (int chunk = 0; chunk < 2; ++chunk) {
        const float* ap = &acc[wid * 16 + l15][chunk * 32 + quad * 8];
        f16x8 af;
        af[0] = (_Float16)ap[0]; af[1] = (_Float16)ap[1];
        af[2] = (_Float16)ap[2]; af[3] = (_Float16)ap[3];
        af[4] = (_Float16)ap[4]; af[5] = (_Float16)ap[5];
        af[6] = (_Float16)ap[6]; af[7] = (_Float16)ap[7];
#pragma unroll
        for (int tt = 0; tt < 8; ++tt) {
            f16x8 bf = *((const f16x8*)(fragbase + (chunk * 8 + tt) * 256));
            accr[tt] = __builtin_amdgcn_mfma_f32_16x16x32_f16(af, bf, accr[tt], 0, 0, 0);
        }
    }

    float bcol[8];
#pragma unroll
    for (int tt = 0; tt < 8; ++tt) bcol[tt] = b2[tt * 16 + l15];
#pragma unroll
    for (int reg = 0; reg < 4; ++reg) {
        int r = nbase + wid * 16 + quad * 4 + reg;
        if (r < N) {
#pragma unroll
            for (int tt = 0; tt < 8; ++tt)
                dout[(size_t)r * 128 + tt * 16 + l15] = accr[tt][reg] + bcol[tt];
        }
    }
}

extern "C" void kernel_launch(void* const* d_in, const int* in_sizes, int n_in,
                              void* d_out, int out_size, void* d_ws, size_t ws_size,
                              hipStream_t stream) {
    const float* x      = (const float*)d_in[0];
    const int*   ei     = (const int*)  d_in[1];
    const float* W1     = (const float*)d_in[2];
    const float* a_src1 = (const float*)d_in[3];
    const float* a_dst1 = (const float*)d_in[4];
    const float* b1     = (const float*)d_in[5];
    const float* W2     = (const float*)d_in[6];
    const float* a_src2 = (const float*)d_in[7];
    const float* a_dst2 = (const float*)d_in[8];
    const float* b2     = (const float*)d_in[9];
    float* dout = (float*)d_out;

    const int N  = in_sizes[0] / 128;
    const int E  = in_sizes[1] / 2;
    const int ET = E + N;                 // edges + self loops
    const int NBUCK = (N + 255) >> 8;     // 196 for N=50000
    const int NBLKA = (ET + 4095) >> 12;  // scatter blocks

    char* wsb = (char*)d_ws;
    _Float16* h1   = (_Float16*)wsb; wsb += (size_t)N * 64 * 2;
    _Float16* out1 = (_Float16*)wsb; wsb += (size_t)N * 64 * 2;
    float* av1  = (float*)wsb; wsb += (size_t)N * 8 * 4;
    float* bv1  = (float*)wsb; wsb += (size_t)N * 8 * 4;
    float* av2  = (float*)wsb; wsb += (size_t)N * 4;
    float* bv2  = (float*)wsb; wsb += (size_t)N * 4;
    float* wa   = (float*)wsb; wsb += 64 * 4;
    float* wb   = (float*)wsb; wsb += 64 * 4;
    unsigned int* bstore = (unsigned int*)wsb; wsb += (size_t)NBUCK * BSTRIDE * 4;
    int* bcur   = (int*)wsb; wsb += 256 * 4;

    const int gblocks = (N + 63) / 64;

    // ---- zero bucket cursors ----
    hipMemsetAsync(bcur, 0, 256 * sizeof(int), stream);

    // ---- 1: merged gemm1 + aux + bucket scatter ----
    g1s_kernel<<<gblocks + 1 + NBLKA, 256, 0, stream>>>(x, W1, a_src1, a_dst1, h1, av1, bv1, N,
                                                        gblocks, W2, a_src2, a_dst2, wa, wb,
                                                        bcur, ei, E, ET, bstore, NBUCK);

    // ---- 2: layer-1 edge-parallel aggregate (half-bucket blocks) ----
    agg1e_kernel<<<NBUCK * 2, 512, 0, stream>>>(bstore, bcur, av1, bv1,
                                                (const __half*)h1, b1, wa, wb,
                                                out1, av2, bv2, N);

    // ---- 3: layer-2 edge-parallel aggregate + fused GEMM ----
    agg2e_kernel<<<NBUCK * 2, 512, 0, stream>>>(bstore, bcur, av2, bv2,
                                                (const __half*)out1, W2, b2, dout, N);
}

// Round 8
// 376.466 us; speedup vs baseline: 2.4047x; 2.4047x over previous
//
#include <hip/hip_runtime.h>
#include <hip/hip_cooperative_groups.h>
#include <hip/hip_fp16.h>
#include <math.h>

namespace cg = cooperative_groups;

#define NEG_SLOPE 0.2f
#define BSTRIDE 6144   // fixed slots per 256-node bucket (mean 4337, 27 sigma margin)
#define L2E 1.4426950408889634f   // log2(e): att coeffs pre-scaled so loops use exp2

typedef _Float16 f16x8 __attribute__((ext_vector_type(8)));
typedef float    f32x4 __attribute__((ext_vector_type(4)));

struct MP {
    const float *x, *W1, *asrc, *adst;
    _Float16 *h1;
    float *av1, *bv1;
    int N, tiles128;
    const float *W2, *as2, *ad2;
    float *wa, *wb;
    int *bcur;
    const int *ei; int E, ET;
    unsigned int *bstore; int nbuck, nblka;
    int *cnt; unsigned short *col;
    const float *b1;
    _Float16 *out1;
    float *av2, *bv2;
    const float *b2;
    float *dout;
    int nitems16;
};

union MegaSMem {
    unsigned int sWu[4096];                                  // gemm staging: 16 KB
    struct { int lhist[256], lbase[256], lrank[256], gbase[256];
             unsigned int sbuf[4096]; int saddr[4096]; } sc; // scatter: 36 KB
    struct { int lrank[256]; } csr;                          // csr rank: 1 KB
};

__device__ __forceinline__ void get_edge(const int* __restrict__ ei, int E, int e,
                                         int& s, int& d) {
    if (e < E) { s = ei[e]; d = ei[E + e]; }
    else       { s = e - E; d = e - E; }
}

// ---------- phase A unit: 128-row gemm1 tile (8 waves x 16 rows) ----------
__device__ void gemm_tile(MegaSMem& sm, const MP& p, int tile) {
    int t = threadIdx.x;
    for (int q = t; q < 4096; q += 512) {
        int frag = q >> 8, lane = (q >> 2) & 63, j2 = q & 3;
        int chunk = frag >> 2, nt = frag & 3;
        int k = chunk * 32 + ((lane >> 4) << 3) + (j2 << 1);
        int n = nt * 16 + (lane & 15);
        union { _Float16 h[2]; unsigned int u; } pk;
        pk.h[0] = (_Float16)p.W1[k * 64 + n];
        pk.h[1] = (_Float16)p.W1[(k + 1) * 64 + n];
        sm.sWu[q] = pk.u;
    }
    __syncthreads();

    int lane = t & 63, wid = t >> 6;
    int rbase = tile * 128 + wid * 16;
    int l15 = lane & 15, quad = lane >> 4;
    int rA = rbase + l15; if (rA >= p.N) rA = p.N - 1;

    const unsigned int* fragbase = &sm.sWu[lane * 4];
    f32x4 z = {0.f, 0.f, 0.f, 0.f};
    f32x4 acc[4] = {z, z, z, z};

#pragma unroll
    for (int chunk = 0; chunk < 4; ++chunk) {
        const float* xp = p.x + (size_t)rA * 128 + chunk * 32 + quad * 8;
        float4 f0 = *((const float4*)xp);
        float4 f1 = *((const float4*)(xp + 4));
        f16x8 af;
        af[0] = (_Float16)f0.x; af[1] = (_Float16)f0.y;
        af[2] = (_Float16)f0.z; af[3] = (_Float16)f0.w;
        af[4] = (_Float16)f1.x; af[5] = (_Float16)f1.y;
        af[6] = (_Float16)f1.z; af[7] = (_Float16)f1.w;
#pragma unroll
        for (int tt = 0; tt < 4; ++tt) {
            f16x8 bf = *((const f16x8*)(fragbase + (chunk * 4 + tt) * 256));
            acc[tt] = __builtin_amdgcn_mfma_f32_16x16x32_f16(af, bf, acc[tt], 0, 0, 0);
        }
    }

    float asc[4], adc[4];
#pragma unroll
    for (int tt = 0; tt < 4; ++tt) {
        asc[tt] = p.asrc[tt * 16 + l15] * L2E;   // pre-scale: agg loops use exp2
        adc[tt] = p.adst[tt * 16 + l15] * L2E;
    }
#pragma unroll
    for (int reg = 0; reg < 4; ++reg) {
        int r = rbase + quad * 4 + reg;
        bool ok = (r < p.N);
#pragma unroll
        for (int tt = 0; tt < 4; ++tt) {
            float v = acc[tt][reg];
            if (ok) p.h1[(size_t)r * 64 + tt * 16 + l15] = (_Float16)v;
            float pa = v * asc[tt], pb = v * adc[tt];
            pa += __shfl_xor(pa, 1); pb += __shfl_xor(pb, 1);
            pa += __shfl_xor(pa, 2); pb += __shfl_xor(pb, 2);
            pa += __shfl_xor(pa, 4); pb += __shfl_xor(pb, 4);
            if (ok && (lane & 7) == 0) {
                int head = tt * 2 + (l15 >> 3);
                p.av1[r * 8 + head] = pa;
                p.bv1[r * 8 + head] = pb;
            }
        }
    }
    __syncthreads();   // LDS may be reused by next unit
}

// ---------- phase A unit: aux (layer-2 att projections, L2E-scaled) ----------
__device__ void aux_unit(const MP& p) {
    int t = threadIdx.x;
    if (t < 64) {
        const float* wr = p.W2 + t * 128;
        float sa = 0.f, sb = 0.f;
#pragma unroll 8
        for (int c = 0; c < 128; ++c) {
            float w = wr[c];
            sa = fmaf(w, p.as2[c], sa);
            sb = fmaf(w, p.ad2[c], sb);
        }
        p.wa[t] = sa * L2E; p.wb[t] = sb * L2E;
    }
}

// ---------- phase A unit: 4096-edge bucket scatter (512 thr, 8 edges/thr) ----------
__device__ void scatter_chunk(MegaSMem& sm, const MP& p, int sblk) {
    int t = threadIdx.x;
    int start = sblk * 4096;
    int cnt_ = p.ET - start; if (cnt_ > 4096) cnt_ = 4096;
    if (t < 256) { sm.sc.lhist[t] = 0; sm.sc.lrank[t] = 0; }
    __syncthreads();
    int mybuck[8]; unsigned int myval[8];
#pragma unroll
    for (int k = 0; k < 8; ++k) {
        int e = start + t + k * 512;
        mybuck[k] = -1;
        if (e < p.ET) {
            int s, d; get_edge(p.ei, p.E, e, s, d);
            mybuck[k] = d >> 8;
            myval[k] = ((unsigned int)d << 16) | (unsigned int)s;
            atomicAdd(&sm.sc.lhist[mybuck[k]], 1);
        }
    }
    __syncthreads();
    int v = 0;
    if (t < 256) { v = sm.sc.lhist[t]; sm.sc.lbase[t] = v; }
    __syncthreads();
    for (int off = 1; off < 256; off <<= 1) {
        int u = (t >= off && t < 256) ? sm.sc.lbase[t - off] : 0;
        __syncthreads();
        if (t < 256) sm.sc.lbase[t] += u;
        __syncthreads();
    }
    if (t < 256) {
        int excl = sm.sc.lbase[t] - v;
        if (t < p.nbuck && v > 0)
            sm.sc.gbase[t] = t * BSTRIDE + atomicAdd(&p.bcur[t], v);
        sm.sc.lbase[t] = excl;
    }
    __syncthreads();
#pragma unroll
    for (int k = 0; k < 8; ++k) {
        int b = mybuck[k];
        if (b >= 0) {
            int r = atomicAdd(&sm.sc.lrank[b], 1);
            int idx = sm.sc.lbase[b] + r;
            sm.sc.sbuf[idx] = myval[k];
            sm.sc.saddr[idx] = sm.sc.gbase[b] + r;
        }
    }
    __syncthreads();
    for (int j = t; j < cnt_; j += 512)
        p.bstore[sm.sc.saddr[j]] = sm.sc.sbuf[j];
    __syncthreads();
}

// ---------- phase B item: rank bucket into 64-slot ushort rows + cnt ----------
__device__ void csr_item(MegaSMem& sm, const MP& p, int b) {
    int t = threadIdx.x;
    int base = b * BSTRIDE;
    int nb = p.bcur[b]; if (nb > BSTRIDE) nb = BSTRIDE;
    if (t < 256) sm.csr.lrank[t] = 0;
    __syncthreads();
    for (int i = t; i < nb; i += 512) {
        unsigned int pk = p.bstore[base + i];
        int local = (pk >> 16) & 255;
        int r = atomicAdd(&sm.csr.lrank[local], 1);
        if (r < 64) p.col[(size_t)(((b << 8) + local) << 6) + r] =
                        (unsigned short)(pk & 0xFFFFu);
    }
    __syncthreads();
    int node = (b << 8) + t;
    if (t < 256 && node < p.N) {
        int deg = sm.csr.lrank[t]; if (deg > 64) deg = 64;
        p.cnt[node] = deg;
    }
    __syncthreads();
}

// ---------- phase C item: 16-node layer-1 softmax-aggregate (R4 body) ----------
__device__ void agg1_item(const MP& p, int item) {
    int t = threadIdx.x;
    int lane = t & 63;
    int node = item * 16 + (t >> 6) * 2 + (lane >> 5);
    bool valid = node < p.N;
    int nodeC = valid ? node : 0;
    int g  = (lane >> 3) & 3;
    int gl = lane & 7;
    const unsigned short* colp = p.col + ((size_t)nodeC << 6);
    int deg = p.cnt[nodeC];
    int last = deg - 1; if (last < 0) last = 0;
    float bd = p.bv1[nodeC * 8 + gl];
    const uint4* hrow = (const uint4*)p.h1;

    uint4 z4 = {0u, 0u, 0u, 0u};
    int e = g;
    int c0 = colp[e      <= last ? e      : last];
    int c1 = colp[e + 4  <= last ? e + 4  : last];
    int c2 = colp[e + 8  <= last ? e + 8  : last];
    float av0 = 0.f, av1v = 0.f; uint4 h0 = z4, h1v = z4;
    if (e < deg)     { av0  = p.av1[c0 * 8 + gl]; h0  = hrow[(size_t)c0 * 8 + gl]; }
    if (e + 4 < deg) { av1v = p.av1[c1 * 8 + gl]; h1v = hrow[(size_t)c1 * 8 + gl]; }

    float s = 0.f, a0 = 0.f, a1 = 0.f, a2 = 0.f, a3 = 0.f,
          a4 = 0.f, a5 = 0.f, a6 = 0.f, a7 = 0.f;
    for (; e < deg; e += 4) {
        float av2v = 0.f; uint4 h2 = z4;
        if (e + 8 < deg) { av2v = p.av1[c2 * 8 + gl]; h2 = hrow[(size_t)c2 * 8 + gl]; }
        int c3 = colp[e + 12 <= last ? e + 12 : last];
        float l = av0 + bd;
        l = l > 0.f ? l : NEG_SLOPE * l;
        float w = __builtin_amdgcn_exp2f(l);
        float2 f0 = __half22float2(*(const __half2*)&h0.x);
        float2 f1 = __half22float2(*(const __half2*)&h0.y);
        float2 f2 = __half22float2(*(const __half2*)&h0.z);
        float2 f3 = __half22float2(*(const __half2*)&h0.w);
        s += w;
        a0 = fmaf(w, f0.x, a0); a1 = fmaf(w, f0.y, a1);
        a2 = fmaf(w, f1.x, a2); a3 = fmaf(w, f1.y, a3);
        a4 = fmaf(w, f2.x, a4); a5 = fmaf(w, f2.y, a5);
        a6 = fmaf(w, f3.x, a6); a7 = fmaf(w, f3.y, a7);
        av0 = av1v; h0 = h1v; av1v = av2v; h1v = h2; c2 = c3;
    }
#pragma unroll
    for (int off = 8; off < 32; off <<= 1) {
        s  += __shfl_xor(s, off);
        a0 += __shfl_xor(a0, off); a1 += __shfl_xor(a1, off);
        a2 += __shfl_xor(a2, off); a3 += __shfl_xor(a3, off);
        a4 += __shfl_xor(a4, off); a5 += __shfl_xor(a5, off);
        a6 += __shfl_xor(a6, off); a7 += __shfl_xor(a7, off);
    }
    float inv = s > 0.f ? __builtin_amdgcn_rcpf(s) : 0.f;
    float4 bb0 = ((const float4*)p.b1)[gl * 2];
    float4 bb1 = ((const float4*)p.b1)[gl * 2 + 1];
    float v0 = a0 * inv + bb0.x, v1 = a1 * inv + bb0.y;
    float v2 = a2 * inv + bb0.z, v3 = a3 * inv + bb0.w;
    float v4 = a4 * inv + bb1.x, v5 = a5 * inv + bb1.y;
    float v6 = a6 * inv + bb1.z, v7 = a7 * inv + bb1.w;
    v0 = v0 > 0.f ? v0 : __expf(v0) - 1.f; v1 = v1 > 0.f ? v1 : __expf(v1) - 1.f;
    v2 = v2 > 0.f ? v2 : __expf(v2) - 1.f; v3 = v3 > 0.f ? v3 : __expf(v3) - 1.f;
    v4 = v4 > 0.f ? v4 : __expf(v4) - 1.f; v5 = v5 > 0.f ? v5 : __expf(v5) - 1.f;
    v6 = v6 > 0.f ? v6 : __expf(v6) - 1.f; v7 = v7 > 0.f ? v7 : __expf(v7) - 1.f;
    float4 wa0 = ((const float4*)p.wa)[gl * 2], wa1 = ((const float4*)p.wa)[gl * 2 + 1];
    float4 wb0 = ((const float4*)p.wb)[gl * 2], wb1 = ((const float4*)p.wb)[gl * 2 + 1];
    float pa = v0 * wa0.x + v1 * wa0.y + v2 * wa0.z + v3 * wa0.w
             + v4 * wa1.x + v5 * wa1.y + v6 * wa1.z + v7 * wa1.w;
    float pb = v0 * wb0.x + v1 * wb0.y + v2 * wb0.z + v3 * wb0.w
             + v4 * wb1.x + v5 * wb1.y + v6 * wb1.z + v7 * wb1.w;
    pa += __shfl_xor(pa, 1); pb += __shfl_xor(pb, 1);
    pa += __shfl_xor(pa, 2); pb += __shfl_xor(pb, 2);
    pa += __shfl_xor(pa, 4); pb += __shfl_xor(pb, 4);
    if (valid && (lane & 31) == 0) { p.av2[node] = pa; p.bv2[node] = pb; }
    if (valid && g == 0) {
        f16x8 o;
        o[0] = (_Float16)v0; o[1] = (_Float16)v1; o[2] = (_Float16)v2; o[3] = (_Float16)v3;
        o[4] = (_Float16)v4; o[5] = (_Float16)v5; o[6] = (_Float16)v6; o[7] = (_Float16)v7;
        ((f16x8*)p.out1)[(size_t)node * 8 + gl] = o;
    }
}

// ---------- phase D: W2 staged once, then 16-node agg2 + MFMA items ----------
__device__ void phaseD(MegaSMem& sm, _Float16 (*sAgg)[72], const MP& p) {
    int t = threadIdx.x;
    for (int q = t; q < 4096; q += 512) {
        int frag = q >> 8, ln = (q >> 2) & 63, j2 = q & 3;
        int chunk = frag >> 3, nt = frag & 7;
        int k = chunk * 32 + ((ln >> 4) << 3) + (j2 << 1);
        int n = nt * 16 + (ln & 15);
        union { _Float16 h[2]; unsigned int u; } pk;
        pk.h[0] = (_Float16)p.W2[k * 128 + n];
        pk.h[1] = (_Float16)p.W2[(k + 1) * 128 + n];
        sm.sWu[q] = pk.u;
    }
    __syncthreads();

    int lane = t & 63, wid = t >> 6;
    int g  = (lane >> 3) & 3;
    int gl = lane & 7;
    int l15 = lane & 15, quad = lane >> 4;
    const uint4* hrow = (const uint4*)p.out1;
    const unsigned int* fragbase = &sm.sWu[lane * 4];
    float bcol = p.b2[wid * 16 + l15];
    uint4 z4 = {0u, 0u, 0u, 0u};

    for (int item = blockIdx.x; item < p.nitems16; item += gridDim.x) {
        int nl = wid * 2 + (lane >> 5);
        int node = item * 16 + nl;
        bool valid = node < p.N;
        int nodeC = valid ? node : 0;
        const unsigned short* colp = p.col + ((size_t)nodeC << 6);
        int deg = p.cnt[nodeC];
        int last = deg - 1; if (last < 0) last = 0;
        float bd = p.bv2[nodeC];

        int e = g;
        int c0 = colp[e      <= last ? e      : last];
        int c1 = colp[e + 4  <= last ? e + 4  : last];
        int c2 = colp[e + 8  <= last ? e + 8  : last];
        float av0 = 0.f, av1v = 0.f; uint4 h0 = z4, h1v = z4;
        if (e < deg)     { av0  = p.av2[c0]; h0  = hrow[(size_t)c0 * 8 + gl]; }
        if (e + 4 < deg) { av1v = p.av2[c1]; h1v = hrow[(size_t)c1 * 8 + gl]; }

        float s = 0.f, a0 = 0.f, a1 = 0.f, a2 = 0.f, a3 = 0.f,
              a4 = 0.f, a5 = 0.f, a6 = 0.f, a7 = 0.f;
        for (; e < deg; e += 4) {
            float av2v = 0.f; uint4 h2 = z4;
            if (e + 8 < deg) { av2v = p.av2[c2]; h2 = hrow[(size_t)c2 * 8 + gl]; }
            int c3 = colp[e + 12 <= last ? e + 12 : last];
            float l = av0 + bd;
            l = l > 0.f ? l : NEG_SLOPE * l;
            float w = __builtin_amdgcn_exp2f(l);
            float2 f0 = __half22float2(*(const __half2*)&h0.x);
            float2 f1 = __half22float2(*(const __half2*)&h0.y);
            float2 f2 = __half22float2(*(const __half2*)&h0.z);
            float2 f3 = __half22float2(*(const __half2*)&h0.w);
            s += w;
            a0 = fmaf(w, f0.x, a0); a1 = fmaf(w, f0.y, a1);
            a2 = fmaf(w, f1.x, a2); a3 = fmaf(w, f1.y, a3);
            a4 = fmaf(w, f2.x, a4); a5 = fmaf(w, f2.y, a5);
            a6 = fmaf(w, f3.x, a6); a7 = fmaf(w, f3.y, a7);
            av0 = av1v; h0 = h1v; av1v = av2v; h1v = h2; c2 = c3;
        }
#pragma unroll
        for (int off = 8; off < 32; off <<= 1) {
            s  += __shfl_xor(s, off);
            a0 += __shfl_xor(a0, off); a1 += __shfl_xor(a1, off);
            a2 += __shfl_xor(a2, off); a3 += __shfl_xor(a3, off);
            a4 += __shfl_xor(a4, off); a5 += __shfl_xor(a5, off);
            a6 += __shfl_xor(a6, off); a7 += __shfl_xor(a7, off);
        }
        if (g == 0) {
            float inv = (valid && s > 0.f) ? __builtin_amdgcn_rcpf(s) : 0.f;
            f16x8 o;
            o[0] = (_Float16)(a0 * inv); o[1] = (_Float16)(a1 * inv);
            o[2] = (_Float16)(a2 * inv); o[3] = (_Float16)(a3 * inv);
            o[4] = (_Float16)(a4 * inv); o[5] = (_Float16)(a5 * inv);
            o[6] = (_Float16)(a6 * inv); o[7] = (_Float16)(a7 * inv);
            *((f16x8*)&sAgg[nl][gl * 8]) = o;
        }
        __syncthreads();

        // MFMA: wave w -> cols w*16..w*16+16, rows item*16..+16, k=64
        f32x4 acc = {0.f, 0.f, 0.f, 0.f};
#pragma unroll
        for (int chunk = 0; chunk < 2; ++chunk) {
            f16x8 af = *((const f16x8*)&sAgg[l15][chunk * 32 + quad * 8]);
            f16x8 bf = *((const f16x8*)(fragbase + (chunk * 8 + wid) * 256));
            acc = __builtin_amdgcn_mfma_f32_16x16x32_f16(af, bf, acc, 0, 0, 0);
        }
#pragma unroll
        for (int reg = 0; reg < 4; ++reg) {
            int r = item * 16 + quad * 4 + reg;
            if (r < p.N)
                p.dout[(size_t)r * 128 + wid * 16 + l15] = acc[reg] + bcol;
        }
        __syncthreads();   // sAgg reused next item
    }
}

__global__ __launch_bounds__(512, 4) void mega_kernel(MP p, int phase) {
    __shared__ MegaSMem sm;
    __shared__ _Float16 sAgg[16][72];

    if (phase < 0 || phase == 0) {
        int UA = p.tiles128 + 1 + p.nblka;
        for (int u = blockIdx.x; u < UA; u += gridDim.x) {
            if (u < p.tiles128)       gemm_tile(sm, p, u);
            else if (u == p.tiles128) aux_unit(p);
            else                      scatter_chunk(sm, p, u - p.tiles128 - 1);
        }
    }
    if (phase < 0) cg::this_grid().sync();
    if (phase < 0 || phase == 1) {
        for (int b = blockIdx.x; b < p.nbuck; b += gridDim.x)
            csr_item(sm, p, b);
    }
    if (phase < 0) cg::this_grid().sync();
    if (phase < 0 || phase == 2) {
        for (int item = blockIdx.x; item < p.nitems16; item += gridDim.x)
            agg1_item(p, item);
    }
    if (phase < 0) cg::this_grid().sync();
    if (phase < 0 || phase == 3) {
        phaseD(sm, sAgg, p);
    }
}

extern "C" void kernel_launch(void* const* d_in, const int* in_sizes, int n_in,
                              void* d_out, int out_size, void* d_ws, size_t ws_size,
                              hipStream_t stream) {
    MP p;
    p.x      = (const float*)d_in[0];
    p.ei     = (const int*)  d_in[1];
    p.W1     = (const float*)d_in[2];
    p.asrc   = (const float*)d_in[3];
    p.adst   = (const float*)d_in[4];
    p.b1     = (const float*)d_in[5];
    p.W2     = (const float*)d_in[6];
    p.as2    = (const float*)d_in[7];
    p.ad2    = (const float*)d_in[8];
    p.b2     = (const float*)d_in[9];
    p.dout   = (float*)d_out;

    p.N  = in_sizes[0] / 128;
    p.E  = in_sizes[1] / 2;
    p.ET = p.E + p.N;
    p.nbuck   = (p.N + 255) >> 8;
    p.nblka   = (p.ET + 4095) >> 12;
    p.tiles128 = (p.N + 127) >> 7;
    p.nitems16 = (p.N + 15) >> 4;

    char* wsb = (char*)d_ws;
    p.h1   = (_Float16*)wsb; wsb += (size_t)p.N * 64 * 2;
    p.out1 = (_Float16*)wsb; wsb += (size_t)p.N * 64 * 2;
    p.av1  = (float*)wsb; wsb += (size_t)p.N * 8 * 4;
    p.bv1  = (float*)wsb; wsb += (size_t)p.N * 8 * 4;
    p.av2  = (float*)wsb; wsb += (size_t)p.N * 4;
    p.bv2  = (float*)wsb; wsb += (size_t)p.N * 4;
    p.wa   = (float*)wsb; wsb += 64 * 4;
    p.wb   = (float*)wsb; wsb += 64 * 4;
    p.cnt  = (int*)wsb; wsb += (size_t)p.N * 4;
    p.col  = (unsigned short*)wsb; wsb += (size_t)p.N * 64 * 2;
    p.bstore = (unsigned int*)wsb; wsb += (size_t)p.nbuck * BSTRIDE * 4;
    p.bcur   = (int*)wsb; wsb += 256 * 4;

    hipMemsetAsync(p.bcur, 0, 256 * sizeof(int), stream);

    int phase = -1;
    void* args[] = { &p, &phase };
    hipError_t err = hipLaunchCooperativeKernel((const void*)mega_kernel,
                                                dim3(512), dim3(512),
                                                args, 0, stream);
    if (err != hipSuccess) {
        (void)hipGetLastError();   // clear sticky error, fall back to split launches
        mega_kernel<<<512, 512, 0, stream>>>(p, 0);
        mega_kernel<<<512, 512, 0, stream>>>(p, 1);
        mega_kernel<<<512, 512, 0, stream>>>(p, 2);
        mega_kernel<<<512, 512, 0, stream>>>(p, 3);
    }
}

// Round 9
// 174.670 us; speedup vs baseline: 5.1829x; 2.1553x over previous
//
#include <hip/hip_runtime.h>
#include <hip/hip_fp16.h>
#include <math.h>

#define NEG_SLOPE 0.2f
#define BSTRIDE 6144   // fixed slots per 256-node bucket (mean 4337, 27 sigma margin)
#define L2E 1.4426950408889634f   // log2(e): att coeffs pre-scaled so loops use exp2

typedef _Float16 f16x8 __attribute__((ext_vector_type(8)));
typedef float    f32x4 __attribute__((ext_vector_type(4)));

__device__ __forceinline__ void get_edge(const int* __restrict__ ei, int E, int e,
                                         int& s, int& d) {
    if (e < E) { s = ei[e]; d = ei[E + e]; }
    else       { s = e - E; d = e - E; }
}

// ========== merged GEMM1 + bucket_scatter (independent work, disjoint blocks) ==========
// blocks [0, gblocks)   : gemm1  h1 = x@W1 (f16) + att1 coeffs (L2E-scaled)
// block  gblocks        : aux: layer-2 att projections wa/wb (L2E-scaled)
// blocks > gblocks      : LDS-staged bucket scatter (global cursors, memset'd)
union G1SMem {
    unsigned int sWu[4096];                                  // gemm path: 16 KB
    struct {
        int lhist[256], lbase[256], lrank[256], gbase[256];  // scatter path
        unsigned int sbuf[4096];
        int saddr[4096];
    } sc;
};

__global__ __launch_bounds__(256) void g1s_kernel(const float* __restrict__ x,
                                                  const float* __restrict__ W,
                                                  const float* __restrict__ asrc,
                                                  const float* __restrict__ adst,
                                                  _Float16* __restrict__ hout,
                                                  float* __restrict__ av,
                                                  float* __restrict__ bv, int N,
                                                  int gblocks,
                                                  const float* __restrict__ W2,
                                                  const float* __restrict__ as2,
                                                  const float* __restrict__ ad2,
                                                  float* __restrict__ wa,
                                                  float* __restrict__ wb,
                                                  int* __restrict__ bcur,
                                                  const int* __restrict__ ei, int E, int ET,
                                                  unsigned int* __restrict__ bstore,
                                                  int nbuck) {
    __shared__ G1SMem sm;
    int t = threadIdx.x;

    if (blockIdx.x == (unsigned)gblocks) {
        // ---- aux: layer-2 attention projections (L2E-scaled) ----
        if (t < 64) {
            const float* wr = W2 + t * 128;
            float sa = 0.f, sb = 0.f;
#pragma unroll 8
            for (int c = 0; c < 128; ++c) {
                float w = wr[c];
                sa = fmaf(w, as2[c], sa);
                sb = fmaf(w, ad2[c], sb);
            }
            wa[t] = sa * L2E; wb[t] = sb * L2E;
        }
        return;
    }

    if (blockIdx.x > (unsigned)gblocks) {
        // ---- bucket scatter (LDS-staged, bucket-grouped writes) ----
        int sblk = blockIdx.x - gblocks - 1;
        int start = sblk * 4096;
        int cnt = ET - start; if (cnt > 4096) cnt = 4096;
        sm.sc.lhist[t] = 0; sm.sc.lrank[t] = 0;
        __syncthreads();
        int mybuck[16]; unsigned int myval[16];
#pragma unroll
        for (int k = 0; k < 16; ++k) {
            int e = start + t + k * 256;
            mybuck[k] = -1;
            if (e < ET) {
                int s, d; get_edge(ei, E, e, s, d);
                mybuck[k] = d >> 8;
                myval[k] = ((unsigned int)d << 16) | (unsigned int)s;
                atomicAdd(&sm.sc.lhist[mybuck[k]], 1);
            }
        }
        __syncthreads();
        int v = sm.sc.lhist[t];
        sm.sc.lbase[t] = v;
        __syncthreads();
        for (int off = 1; off < 256; off <<= 1) {
            int u = (t >= off) ? sm.sc.lbase[t - off] : 0;
            __syncthreads();
            sm.sc.lbase[t] += u;
            __syncthreads();
        }
        int excl = sm.sc.lbase[t] - v;
        if (t < nbuck && v > 0)
            sm.sc.gbase[t] = t * BSTRIDE + atomicAdd(&bcur[t], v);
        __syncthreads();
        sm.sc.lbase[t] = excl;
        __syncthreads();
#pragma unroll
        for (int k = 0; k < 16; ++k) {
            int b = mybuck[k];
            if (b >= 0) {
                int r = atomicAdd(&sm.sc.lrank[b], 1);
                int idx = sm.sc.lbase[b] + r;
                sm.sc.sbuf[idx] = myval[k];
                sm.sc.saddr[idx] = sm.sc.gbase[b] + r;
            }
        }
        __syncthreads();
        for (int j = t; j < cnt; j += 256)
            bstore[sm.sc.saddr[j]] = sm.sc.sbuf[j];
        return;
    }

    // ---- gemm1 ----
    for (int p = t; p < 4096; p += 256) {
        int frag = p >> 8;
        int lane = (p >> 2) & 63;
        int j2   = p & 3;
        int chunk = frag >> 2, nt = frag & 3;
        int k = chunk * 32 + ((lane >> 4) << 3) + (j2 << 1);
        int n = nt * 16 + (lane & 15);
        union { _Float16 h[2]; unsigned int u; } pk;
        pk.h[0] = (_Float16)W[k * 64 + n];
        pk.h[1] = (_Float16)W[(k + 1) * 64 + n];
        sm.sWu[p] = pk.u;
    }
    __syncthreads();

    int lane = t & 63;
    int wid  = t >> 6;
    int rbase = blockIdx.x * 64 + wid * 16;
    int l15 = lane & 15, quad = lane >> 4;
    int rA = rbase + l15; if (rA >= N) rA = N - 1;

    const unsigned int* fragbase = &sm.sWu[lane * 4];
    f32x4 z = {0.f, 0.f, 0.f, 0.f};
    f32x4 acc[4] = {z, z, z, z};

#pragma unroll
    for (int chunk = 0; chunk < 4; ++chunk) {
        const float* xp = x + (size_t)rA * 128 + chunk * 32 + quad * 8;
        float4 f0 = *((const float4*)xp);
        float4 f1 = *((const float4*)(xp + 4));
        f16x8 af;
        af[0] = (_Float16)f0.x; af[1] = (_Float16)f0.y;
        af[2] = (_Float16)f0.z; af[3] = (_Float16)f0.w;
        af[4] = (_Float16)f1.x; af[5] = (_Float16)f1.y;
        af[6] = (_Float16)f1.z; af[7] = (_Float16)f1.w;
#pragma unroll
        for (int tt = 0; tt < 4; ++tt) {
            f16x8 bf = *((const f16x8*)(fragbase + (chunk * 4 + tt) * 256));
            acc[tt] = __builtin_amdgcn_mfma_f32_16x16x32_f16(af, bf, acc[tt], 0, 0, 0);
        }
    }

    float asc[4], adc[4];
#pragma unroll
    for (int tt = 0; tt < 4; ++tt) {
        asc[tt] = asrc[tt * 16 + l15] * L2E;   // pre-scale: agg loop uses native exp2
        adc[tt] = adst[tt * 16 + l15] * L2E;
    }
#pragma unroll
    for (int reg = 0; reg < 4; ++reg) {
        int r = rbase + quad * 4 + reg;
        bool ok = (r < N);
#pragma unroll
        for (int tt = 0; tt < 4; ++tt) {
            float v = acc[tt][reg];
            if (ok) hout[(size_t)r * 64 + tt * 16 + l15] = (_Float16)v;
            float pa = v * asc[tt], pb = v * adc[tt];
            pa += __shfl_xor(pa, 1); pb += __shfl_xor(pb, 1);
            pa += __shfl_xor(pa, 2); pb += __shfl_xor(pb, 2);
            pa += __shfl_xor(pa, 4); pb += __shfl_xor(pb, 4);
            if (ok && (lane & 7) == 0) {
                int head = tt * 2 + (l15 >> 3);
                av[r * 8 + head] = pa;
                bv[r * 8 + head] = pb;
            }
        }
    }
}

// ========== bucket_csr64: one pass; emits fixed-64-slot ushort rows + cnt ==========
__global__ __launch_bounds__(256) void bucket_csr64(const unsigned int* __restrict__ bstore,
                                                    const int* __restrict__ bcur,
                                                    int* __restrict__ cnt,
                                                    unsigned short* __restrict__ col, int N) {
    __shared__ int lrank[256];
    int b = blockIdx.x, t = threadIdx.x;
    int base = b * BSTRIDE;
    int nb = bcur[b]; if (nb > BSTRIDE) nb = BSTRIDE;
    lrank[t] = 0;
    __syncthreads();
    for (int i = t; i < nb; i += 256) {
        unsigned int pk = bstore[base + i];
        int local = (pk >> 16) & 255;
        int r = atomicAdd(&lrank[local], 1);
        if (r < 64) col[(((b << 8) + local) << 6) + r] = (unsigned short)(pk & 0xFFFFu);
    }
    __syncthreads();
    int node = (b << 8) + t;
    if (node < N) {
        int deg = lrank[t]; if (deg > 64) deg = 64;
        cnt[node] = deg;
    }
}

// ========== fused layer-1 softmax-aggregate + layer-2 att coeffs ==========
// 2 nodes per wave: lanes 0-31 = node A, 32-63 = node B. Per node: 4 groups
// of 8 lanes own edges e = g, step 4. Cross-group reduce: 2 stages (off=8,16).
__global__ __launch_bounds__(512) void agg1_kernel(const int* __restrict__ cnt,
                                                   const unsigned short* __restrict__ col,
                                                   const float* __restrict__ av,
                                                   const float* __restrict__ bv,
                                                   const __half* __restrict__ h1,
                                                   const float* __restrict__ b1,
                                                   const float* __restrict__ wa,
                                                   const float* __restrict__ wb,
                                                   _Float16* __restrict__ out1,
                                                   float* __restrict__ av2,
                                                   float* __restrict__ bv2, int N) {
    int lane = threadIdx.x & 63;
    int node = blockIdx.x * 16 + (threadIdx.x >> 6) * 2 + (lane >> 5);
    bool valid = node < N;
    int nodeC = valid ? node : 0;
    int g  = (lane >> 3) & 3;
    int gl = lane & 7;
    const unsigned short* colp = col + ((size_t)nodeC << 6);
    int deg = cnt[nodeC];
    int last = deg - 1; if (last < 0) last = 0;
    float bd = bv[nodeC * 8 + gl];
    const uint4* hrow = (const uint4*)h1;

    uint4 z4 = {0u, 0u, 0u, 0u};
    int e = g;
    int c0 = colp[e      <= last ? e      : last];
    int c1 = colp[e + 4  <= last ? e + 4  : last];
    int c2 = colp[e + 8  <= last ? e + 8  : last];
    float av0 = 0.f, av1v = 0.f; uint4 h0 = z4, h1v = z4;
    if (e < deg)     { av0  = av[c0 * 8 + gl]; h0  = hrow[(size_t)c0 * 8 + gl]; }
    if (e + 4 < deg) { av1v = av[c1 * 8 + gl]; h1v = hrow[(size_t)c1 * 8 + gl]; }

    float s = 0.f, a0 = 0.f, a1 = 0.f, a2 = 0.f, a3 = 0.f,
          a4 = 0.f, a5 = 0.f, a6 = 0.f, a7 = 0.f;
    for (; e < deg; e += 4) {
        float av2v = 0.f; uint4 h2 = z4;
        if (e + 8 < deg) { av2v = av[c2 * 8 + gl]; h2 = hrow[(size_t)c2 * 8 + gl]; }
        int c3 = colp[e + 12 <= last ? e + 12 : last];
        float l = av0 + bd;
        l = l > 0.f ? l : NEG_SLOPE * l;
        float w = __builtin_amdgcn_exp2f(l);
        float2 f0 = __half22float2(*(const __half2*)&h0.x);
        float2 f1 = __half22float2(*(const __half2*)&h0.y);
        float2 f2 = __half22float2(*(const __half2*)&h0.z);
        float2 f3 = __half22float2(*(const __half2*)&h0.w);
        s += w;
        a0 = fmaf(w, f0.x, a0); a1 = fmaf(w, f0.y, a1);
        a2 = fmaf(w, f1.x, a2); a3 = fmaf(w, f1.y, a3);
        a4 = fmaf(w, f2.x, a4); a5 = fmaf(w, f2.y, a5);
        a6 = fmaf(w, f3.x, a6); a7 = fmaf(w, f3.y, a7);
        av0 = av1v; h0 = h1v; av1v = av2v; h1v = h2; c2 = c3;
    }
#pragma unroll
    for (int off = 8; off < 32; off <<= 1) {
        s  += __shfl_xor(s, off);
        a0 += __shfl_xor(a0, off); a1 += __shfl_xor(a1, off);
        a2 += __shfl_xor(a2, off); a3 += __shfl_xor(a3, off);
        a4 += __shfl_xor(a4, off); a5 += __shfl_xor(a5, off);
        a6 += __shfl_xor(a6, off); a7 += __shfl_xor(a7, off);
    }
    float inv = __builtin_amdgcn_rcpf(s);
    float4 bb0 = ((const float4*)b1)[gl * 2];
    float4 bb1 = ((const float4*)b1)[gl * 2 + 1];
    float v0 = a0 * inv + bb0.x, v1 = a1 * inv + bb0.y;
    float v2 = a2 * inv + bb0.z, v3 = a3 * inv + bb0.w;
    float v4 = a4 * inv + bb1.x, v5 = a5 * inv + bb1.y;
    float v6 = a6 * inv + bb1.z, v7 = a7 * inv + bb1.w;
    v0 = v0 > 0.f ? v0 : __expf(v0) - 1.f; v1 = v1 > 0.f ? v1 : __expf(v1) - 1.f;
    v2 = v2 > 0.f ? v2 : __expf(v2) - 1.f; v3 = v3 > 0.f ? v3 : __expf(v3) - 1.f;
    v4 = v4 > 0.f ? v4 : __expf(v4) - 1.f; v5 = v5 > 0.f ? v5 : __expf(v5) - 1.f;
    v6 = v6 > 0.f ? v6 : __expf(v6) - 1.f; v7 = v7 > 0.f ? v7 : __expf(v7) - 1.f;
    float4 wa0 = ((const float4*)wa)[gl * 2], wa1 = ((const float4*)wa)[gl * 2 + 1];
    float4 wb0 = ((const float4*)wb)[gl * 2], wb1 = ((const float4*)wb)[gl * 2 + 1];
    float pa = v0 * wa0.x + v1 * wa0.y + v2 * wa0.z + v3 * wa0.w
             + v4 * wa1.x + v5 * wa1.y + v6 * wa1.z + v7 * wa1.w;
    float pb = v0 * wb0.x + v1 * wb0.y + v2 * wb0.z + v3 * wb0.w
             + v4 * wb1.x + v5 * wb1.y + v6 * wb1.z + v7 * wb1.w;
    pa += __shfl_xor(pa, 1); pb += __shfl_xor(pb, 1);
    pa += __shfl_xor(pa, 2); pb += __shfl_xor(pb, 2);
    pa += __shfl_xor(pa, 4); pb += __shfl_xor(pb, 4);
    if (valid && (lane & 31) == 0) { av2[node] = pa; bv2[node] = pb; }
    if (valid && g == 0) {
        f16x8 o;
        o[0] = (_Float16)v0; o[1] = (_Float16)v1; o[2] = (_Float16)v2; o[3] = (_Float16)v3;
        o[4] = (_Float16)v4; o[5] = (_Float16)v5; o[6] = (_Float16)v6; o[7] = (_Float16)v7;
        ((f16x8*)out1)[(size_t)node * 8 + gl] = o;
    }
}

// ========== fused layer-2: aggregate 64 nodes into LDS, then MFMA @ W2 -> dout ==========
__global__ __launch_bounds__(512) void agg2g2_kernel(const int* __restrict__ cnt,
                                                     const unsigned short* __restrict__ col,
                                                     const float* __restrict__ av,
                                                     const float* __restrict__ bv,
                                                     const __half* __restrict__ out1,
                                                     const float* __restrict__ W,
                                                     const float* __restrict__ b2,
                                                     float* __restrict__ dout, int N) {
    __shared__ unsigned int sWu[4096];      // 16 KB W2 frags
    __shared__ _Float16 sAgg[64][72];       // 18 KB padded agg tile
    int t = threadIdx.x;
    int lane = t & 63;
    int wid  = t >> 6;
    int rbase = blockIdx.x * 64;

    // ---- phase 0: stage W2 ----
    for (int p = t; p < 4096; p += 512) {
        int frag = p >> 8;
        int ln = (p >> 2) & 63;
        int j2 = p & 3;
        int chunk = frag >> 3, nt = frag & 7;
        int k = chunk * 32 + ((ln >> 4) << 3) + (j2 << 1);
        int n = nt * 16 + (ln & 15);
        union { _Float16 h[2]; unsigned int u; } pk;
        pk.h[0] = (_Float16)W[k * 128 + n];
        pk.h[1] = (_Float16)W[(k + 1) * 128 + n];
        sWu[p] = pk.u;
    }

    // ---- phase 1: aggregate 64 nodes (8 waves x 2 nodes x 4 passes) ----
    int g  = (lane >> 3) & 3;
    int gl = lane & 7;
    const uint4* hrow = (const uint4*)out1;
    uint4 z4 = {0u, 0u, 0u, 0u};
#pragma unroll 1
    for (int pass = 0; pass < 4; ++pass) {
        int nl = pass * 16 + wid * 2 + (lane >> 5);
        int node = rbase + nl;
        bool valid = node < N;
        int nodeC = valid ? node : 0;
        const unsigned short* colp = col + ((size_t)nodeC << 6);
        int deg = cnt[nodeC];
        int last = deg - 1; if (last < 0) last = 0;
        float bd = bv[nodeC];

        int e = g;
        int c0 = colp[e      <= last ? e      : last];
        int c1 = colp[e + 4  <= last ? e + 4  : last];
        int c2 = colp[e + 8  <= last ? e + 8  : last];
        float av0 = 0.f, av1v = 0.f; uint4 h0 = z4, h1v = z4;
        if (e < deg)     { av0  = av[c0]; h0  = hrow[(size_t)c0 * 8 + gl]; }
        if (e + 4 < deg) { av1v = av[c1]; h1v = hrow[(size_t)c1 * 8 + gl]; }

        float s = 0.f, a0 = 0.f, a1 = 0.f, a2 = 0.f, a3 = 0.f,
              a4 = 0.f, a5 = 0.f, a6 = 0.f, a7 = 0.f;
        for (; e < deg; e += 4) {
            float av2v = 0.f; uint4 h2 = z4;
            if (e + 8 < deg) { av2v = av[c2]; h2 = hrow[(size_t)c2 * 8 + gl]; }
            int c3 = colp[e + 12 <= last ? e + 12 : last];
            float l = av0 + bd;
            l = l > 0.f ? l : NEG_SLOPE * l;
            float w = __builtin_amdgcn_exp2f(l);
            float2 f0 = __half22float2(*(const __half2*)&h0.x);
            float2 f1 = __half22float2(*(const __half2*)&h0.y);
            float2 f2 = __half22float2(*(const __half2*)&h0.z);
            float2 f3 = __half22float2(*(const __half2*)&h0.w);
            s += w;
            a0 = fmaf(w, f0.x, a0); a1 = fmaf(w, f0.y, a1);
            a2 = fmaf(w, f1.x, a2); a3 = fmaf(w, f1.y, a3);
            a4 = fmaf(w, f2.x, a4); a5 = fmaf(w, f2.y, a5);
            a6 = fmaf(w, f3.x, a6); a7 = fmaf(w, f3.y, a7);
            av0 = av1v; h0 = h1v; av1v = av2v; h1v = h2; c2 = c3;
        }
#pragma unroll
        for (int off = 8; off < 32; off <<= 1) {
            s  += __shfl_xor(s, off);
            a0 += __shfl_xor(a0, off); a1 += __shfl_xor(a1, off);
            a2 += __shfl_xor(a2, off); a3 += __shfl_xor(a3, off);
            a4 += __shfl_xor(a4, off); a5 += __shfl_xor(a5, off);
            a6 += __shfl_xor(a6, off); a7 += __shfl_xor(a7, off);
        }
        if (g == 0) {
            float inv = __builtin_amdgcn_rcpf(s);
            f16x8 o;
            o[0] = (_Float16)(a0 * inv); o[1] = (_Float16)(a1 * inv);
            o[2] = (_Float16)(a2 * inv); o[3] = (_Float16)(a3 * inv);
            o[4] = (_Float16)(a4 * inv); o[5] = (_Float16)(a5 * inv);
            o[6] = (_Float16)(a6 * inv); o[7] = (_Float16)(a7 * inv);
            *((f16x8*)&sAgg[nl][gl * 8]) = o;
        }
    }
    __syncthreads();

    // ---- phase 2: MFMA. wave w: rows (w&3)*16, cols (w>>2)*64 ----
    int rblk = (wid & 3) * 16;
    int chalf = wid >> 2;
    int l15 = lane & 15, quad = lane >> 4;

    const unsigned int* fragbase = &sWu[lane * 4];
    f32x4 z = {0.f, 0.f, 0.f, 0.f};
    f32x4 acc[4] = {z, z, z, z};

#pragma unroll
    for (int chunk = 0; chunk < 2; ++chunk) {
        f16x8 af = *((const f16x8*)&sAgg[rblk + l15][chunk * 32 + quad * 8]);
#pragma unroll
        for (int tt = 0; tt < 4; ++tt) {
            f16x8 bf = *((const f16x8*)(fragbase + (chunk * 8 + chalf * 4 + tt) * 256));
            acc[tt] = __builtin_amdgcn_mfma_f32_16x16x32_f16(af, bf, acc[tt], 0, 0, 0);
        }
    }

    float bcol[4];
#pragma unroll
    for (int tt = 0; tt < 4; ++tt) bcol[tt] = b2[chalf * 64 + tt * 16 + l15];
#pragma unroll
    for (int reg = 0; reg < 4; ++reg) {
        int r = rbase + rblk + quad * 4 + reg;
        if (r < N) {
#pragma unroll
            for (int tt = 0; tt < 4; ++tt)
                dout[(size_t)r * 128 + chalf * 64 + tt * 16 + l15] = acc[tt][reg] + bcol[tt];
        }
    }
}

extern "C" void kernel_launch(void* const* d_in, const int* in_sizes, int n_in,
                              void* d_out, int out_size, void* d_ws, size_t ws_size,
                              hipStream_t stream) {
    const float* x      = (const float*)d_in[0];
    const int*   ei     = (const int*)  d_in[1];
    const float* W1     = (const float*)d_in[2];
    const float* a_src1 = (const float*)d_in[3];
    const float* a_dst1 = (const float*)d_in[4];
    const float* b1     = (const float*)d_in[5];
    const float* W2     = (const float*)d_in[6];
    const float* a_src2 = (const float*)d_in[7];
    const float* a_dst2 = (const float*)d_in[8];
    const float* b2     = (const float*)d_in[9];
    float* dout = (float*)d_out;

    const int N  = in_sizes[0] / 128;
    const int E  = in_sizes[1] / 2;
    const int ET = E + N;                 // edges + self loops
    const int NBUCK = (N + 255) >> 8;     // 196 for N=50000
    const int NBLKA = (ET + 4095) >> 12;  // scatter blocks

    char* wsb = (char*)d_ws;
    _Float16* h1     = (_Float16*)wsb; wsb += (size_t)N * 64 * 2;
    _Float16* out1   = (_Float16*)wsb; wsb += (size_t)N * 64 * 2;
    float* av1  = (float*)wsb; wsb += (size_t)N * 8 * 4;
    float* bv1  = (float*)wsb; wsb += (size_t)N * 8 * 4;
    float* av2  = (float*)wsb; wsb += (size_t)N * 4;
    float* bv2  = (float*)wsb; wsb += (size_t)N * 4;
    float* wa   = (float*)wsb; wsb += 64 * 4;
    float* wb   = (float*)wsb; wsb += 64 * 4;
    int* cnt    = (int*)wsb; wsb += (size_t)N * 4;
    unsigned short* col = (unsigned short*)wsb; wsb += (size_t)N * 64 * 2;
    unsigned int* bstore = (unsigned int*)wsb; wsb += (size_t)NBUCK * BSTRIDE * 4;
    int* bcur   = (int*)wsb; wsb += 256 * 4;

    const int gblocks = (N + 63) / 64;

    // ---- zero bucket cursors ----
    hipMemsetAsync(bcur, 0, 256 * sizeof(int), stream);

    // ---- merged gemm1 + aux + bucket scatter (independent, co-resident) ----
    g1s_kernel<<<gblocks + 1 + NBLKA, 256, 0, stream>>>(x, W1, a_src1, a_dst1, h1, av1, bv1, N,
                                                        gblocks, W2, a_src2, a_dst2, wa, wb,
                                                        bcur, ei, E, ET, bstore, NBUCK);

    // ---- rank into fixed 64-slot ushort rows ----
    bucket_csr64<<<NBUCK, 256, 0, stream>>>(bstore, bcur, cnt, col, N);

    // ---- layer 1 aggregate (16 nodes/block, 2 per wave) ----
    agg1_kernel<<<(N + 15) / 16, 512, 0, stream>>>(cnt, col, av1, bv1,
                                                   (const __half*)h1, b1, wa, wb,
                                                   out1, av2, bv2, N);

    // ---- layer 2 fused aggregate + GEMM ----
    agg2g2_kernel<<<gblocks, 512, 0, stream>>>(cnt, col, av2, bv2,
                                               (const __half*)out1, W2, b2, dout, N);
}